// Round 17
// baseline (148.986 us; speedup 1.0000x reference)
//
#include <hip/hip_runtime.h>
#include <stdint.h>

// Problem constants: B=16, K=8, F=512, INCH=512, OUTCH=512, R=8
// rows M = B*K*F = 65536; "bk" index = b*8+k (128 slices of 512 rows)
// Algebra: h = [hp | gy_bcast]; out = gelu(hp @ WoL^T + G2[b,f] + b + z.u^T/8),
//          G2 = gy @ WoR^T + b_out;  z = (hp.vL + gy.vR)/512
// Round 17: de-fused. 64 KB-LDS GEMMs (2 blocks/CU), BK=64 race-free two-barrier
// steps, shared staging, G2 factorization (out-GEMM K=256 -> 4 steps).

typedef __attribute__((ext_vector_type(8))) __bf16 bf16x8;
typedef __attribute__((ext_vector_type(4))) float f32x4;
typedef __attribute__((ext_vector_type(8))) unsigned short ushort8;
typedef __attribute__((ext_vector_type(4))) unsigned short ushort4_t;
typedef __attribute__((ext_vector_type(4))) float float4_t;

#define MFMA16(a, b, c) __builtin_amdgcn_mfma_f32_16x16x32_bf16((a), (b), (c), 0, 0, 0)
#define GLL16(g, l)                                                                   \
    __builtin_amdgcn_global_load_lds((const __attribute__((address_space(1))) void*)(g), \
                                     (__attribute__((address_space(3))) void*)(l), 16, 0, 0)

__device__ inline unsigned short f2bf(float f) {
    union { float fv; unsigned u; } un; un.fv = f;
    unsigned u = un.u;
    u += 0x7FFFu + ((u >> 16) & 1u);   // RNE
    return (unsigned short)(u >> 16);
}

// fast gelu: x * sigmoid(1.5957691*(x + 0.044715 x^3)); max |err| vs exact ~2.5e-4
__device__ inline float geluf(float x) {
    float x2 = x * x;
    float inner = x + 0.044715f * x * x2;
    float e = __expf(-1.5957691216057308f * inner);
    return x * __builtin_amdgcn_rcpf(1.0f + e);
}

__device__ inline bf16x8 lds8(const unsigned short* p) {
    return __builtin_bit_cast(bf16x8, *(const ushort8*)p);
}

// ---- chunk-granular staging: chunk c = 16 rows x 32 k = one GLL16 per wave.
// logical k-granule j of row r lives at phys slot j ^ (r&3) ^ ((r>>2)&3);
// swizzle via per-lane GLOBAL source addr, LDS dest linear (GLL16 rule).
__device__ inline void stage_chunk(const unsigned short* __restrict__ src, long rowbase,
                                   long stride, int k0, unsigned short* buf, int c, int l) {
    const int r = c * 16 + (l >> 2);
    const int j = (l & 3) ^ ((l >> 2) & 3) ^ (l >> 4);
    GLL16(src + (rowbase + r) * stride + k0 + j * 8, &buf[c * 512]);
}

// read logical (row rbase+(l&15), granule l>>4) from a chunked [rows][32] buf
__device__ inline bf16x8 ldf2(const unsigned short* buf, int rbase, int l) {
    const int r = rbase + (l & 15);
    const int slot = (l >> 4) ^ (r & 3) ^ ((r >> 2) & 3);
    return lds8(&buf[r * 32 + slot * 8]);
}

// ---- per-WAVE private 64x32 staging (r9 structure; wave reads only its own
// staged chunks -> per-wave vmcnt is a sufficient fence) -------------------------
__device__ inline void stage_w(const unsigned short* __restrict__ src, long rowbase,
                               long stride, int k0, unsigned short* buf, int l) {
#pragma unroll
    for (int it = 0; it < 4; ++it) {
        const int s = it * 64 + l;
        const int r = s >> 2;
        const int j = (s & 3) ^ (r & 3);
        GLL16(src + (rowbase + r) * stride + k0 + j * 8, &buf[it * 512]);
    }
}

__device__ inline bf16x8 ldw(const unsigned short* buf, int rbase, int l) {
    const int r = rbase + (l & 15);
    const int j = l >> 4;
    return lds8(&buf[r * 32 + (((j ^ r) & 3) << 3)]);
}

// ---------------- K0: all three weight mats fp32 -> bf16 in one launch ----------
__global__ void cvt_all(const float* __restrict__ a, const float* __restrict__ b,
                        const float* __restrict__ c, unsigned short* __restrict__ oa,
                        unsigned short* __restrict__ ob, unsigned short* __restrict__ oc) {
    int bid = blockIdx.x;                // 512 blocks: 128 Wp, 128 Wa, 256 Wo
    const float* s; unsigned short* d; int off;
    if (bid < 128) { s = a; d = oa; off = bid; }
    else if (bid < 256) { s = b; d = ob; off = bid - 128; }
    else { s = c; d = oc; off = bid - 256; }
    int i = off * 256 + threadIdx.x;     // float4 index
    float4_t v = *(const float4_t*)(s + (size_t)i * 4);
    ushort4_t r;
    r[0] = f2bf(v[0]); r[1] = f2bf(v[1]); r[2] = f2bf(v[2]); r[3] = f2bf(v[3]);
    *(ushort4_t*)(d + (size_t)i * 4) = r;
}

// ---------------- K1: mean over K + x -> bf16, 16B stores.  grid 2048 x 256 -----
__global__ void mean_cvt(const float* __restrict__ x,
                         unsigned short* __restrict__ xb,
                         unsigned short* __restrict__ xm) {
    int gid = blockIdx.x * 256 + threadIdx.x;   // B*F*64 = 524288 threads
    int c  = gid & 63;
    int bf = gid >> 6;
    int b  = bf >> 9;
    int f  = bf & 511;
    float s0 = 0.f, s1 = 0.f, s2 = 0.f, s3 = 0.f, s4 = 0.f, s5 = 0.f, s6 = 0.f, s7 = 0.f;
#pragma unroll
    for (int k = 0; k < 8; ++k) {
        long row = (long)(b * 8 + k) * 512 + f;
        float4_t lo = *(const float4_t*)(x + row * 512 + c * 8);
        float4_t hi = *(const float4_t*)(x + row * 512 + c * 8 + 4);
        s0 += lo[0]; s1 += lo[1]; s2 += lo[2]; s3 += lo[3];
        s4 += hi[0]; s5 += hi[1]; s6 += hi[2]; s7 += hi[3];
        ushort8 t;
        t[0] = f2bf(lo[0]); t[1] = f2bf(lo[1]); t[2] = f2bf(lo[2]); t[3] = f2bf(lo[3]);
        t[4] = f2bf(hi[0]); t[5] = f2bf(hi[1]); t[6] = f2bf(hi[2]); t[7] = f2bf(hi[3]);
        *(ushort8*)(xb + row * 512 + c * 8) = t;
    }
    ushort8 m;
    m[0] = f2bf(s0 * 0.125f); m[1] = f2bf(s1 * 0.125f);
    m[2] = f2bf(s2 * 0.125f); m[3] = f2bf(s3 * 0.125f);
    m[4] = f2bf(s4 * 0.125f); m[5] = f2bf(s5 * 0.125f);
    m[6] = f2bf(s6 * 0.125f); m[7] = f2bf(s7 * 0.125f);
    *(ushort8*)(xm + (long)bf * 512 + c * 8) = m;
}

// ------- K2: gy[8192][256] = gelu(xm @ Wa^T + ba) — r9 structure (wave-private) -
__launch_bounds__(256)
__global__ void gemm_gelu(const unsigned short* __restrict__ A,
                          const unsigned short* __restrict__ W,
                          const float* __restrict__ bias,
                          unsigned short* __restrict__ O,
                          int chunk) {
    __shared__ __align__(16) unsigned short S[32768];
    const int tid = threadIdx.x;
    const int w = tid >> 6, l = tid & 63;
    const int wr = w >> 1, wc = w & 1;
    const int work = ((blockIdx.x & 7) * chunk) + (blockIdx.x >> 3);
    const int nt = work & 1;
    const int mt = work >> 1;
    const long row0 = (long)mt * 128 + wr * 64;
    const long col0 = (long)nt * 128 + wc * 64;

    unsigned short* aw[2] = { &S[w * 4096],        &S[16384 + w * 4096] };
    unsigned short* bw[2] = { &S[w * 4096 + 2048], &S[16384 + w * 4096 + 2048] };

    f32x4 acc[4][4];
    const f32x4 z4 = {0.f, 0.f, 0.f, 0.f};
#pragma unroll
    for (int i = 0; i < 4; ++i)
#pragma unroll
        for (int j = 0; j < 4; ++j) acc[i][j] = z4;

    stage_w(A, row0, 512, 0, aw[0], l);
    stage_w(W, col0, 512, 0, bw[0], l);

#pragma unroll
    for (int t = 0; t < 16; ++t) {
        if (t < 15) {
            stage_w(A, row0, 512, (t + 1) * 32, aw[(t + 1) & 1], l);
            stage_w(W, col0, 512, (t + 1) * 32, bw[(t + 1) & 1], l);
            asm volatile("s_waitcnt vmcnt(8)" ::: "memory");
        } else {
            asm volatile("s_waitcnt vmcnt(0)" ::: "memory");
        }
        const unsigned short* ab = aw[t & 1];
        const unsigned short* bbuf = bw[t & 1];
        bf16x8 af[4], bfr[4];
#pragma unroll
        for (int mi = 0; mi < 4; ++mi) af[mi] = ldw(ab, mi * 16, l);
#pragma unroll
        for (int nj = 0; nj < 4; ++nj) bfr[nj] = ldw(bbuf, nj * 16, l);
        __builtin_amdgcn_s_setprio(1);
#pragma unroll
        for (int mi = 0; mi < 4; ++mi)
#pragma unroll
            for (int nj = 0; nj < 4; ++nj)
                acc[mi][nj] = MFMA16(af[mi], bfr[nj], acc[mi][nj]);
        __builtin_amdgcn_s_setprio(0);
    }

    __syncthreads();
    const int colblk = nt * 128;
#pragma unroll
    for (int mi = 0; mi < 4; ++mi) {
        const int R0 = wr * 64 + mi * 16 + (l >> 4) * 4;
#pragma unroll
        for (int nj = 0; nj < 4; ++nj) {
            const int C = wc * 64 + nj * 16 + (l & 15);
            const float bv = bias[colblk + C];
#pragma unroll
            for (int q = 0; q < 4; ++q)
                S[(R0 + q) * 136 + C] = f2bf(geluf(acc[mi][nj][q] + bv));
        }
    }
    __syncthreads();
    const long rowt = (long)mt * 128;
#pragma unroll
    for (int s = 0; s < 8; ++s) {
        const int flat = s * 2048 + tid * 8;
        const int row = flat >> 7;
        const int col = flat & 127;
        ushort8 vv = *(const ushort8*)&S[row * 136 + col];
        *(ushort8*)(O + (rowt + row) * 256 + colblk + col) = vv;
    }
}

// ---- K3: hp[65536][256] = gelu(xb @ Wp^T + bp). 128x128 tile, BK=64, 8 steps,
// shared staging, race-free two-barrier: [STG(t+1); vmcnt(own)] ; bar ; comp ; bar
__launch_bounds__(256)
__global__ void gemm_hp(const unsigned short* __restrict__ A,    // xb [65536][512]
                        const unsigned short* __restrict__ W,    // Wpb [256][512]
                        const float* __restrict__ bias,          // bp [256]
                        unsigned short* __restrict__ O) {        // hp [65536][256]
    __shared__ __align__(16) unsigned short S[32768];   // 64 KB: buf(t&1) @ (t&1)*16384
    const int tid = threadIdx.x;
    const int w = tid >> 6, l = tid & 63;
    const int wr = w >> 1, wc = w & 1;
    const int work = ((blockIdx.x & 7) * 128) + (blockIdx.x >> 3);  // 1024 wgs
    const int nt = work & 1;
    const int mt = work >> 1;
    const long row0 = (long)mt * 128;
    const long colb = (long)nt * 128;

    f32x4 acc[4][4];
    const f32x4 z4 = {0.f, 0.f, 0.f, 0.f};
#pragma unroll
    for (int i = 0; i < 4; ++i)
#pragma unroll
        for (int j = 0; j < 4; ++j) acc[i][j] = z4;

    // buf layout (16384 ushorts): A-klo @0, A-khi @4096, B-klo @8192, B-khi @12288
#define STGH(t)                                                               \
    {                                                                         \
        unsigned short* b_ = &S[((t) & 1) * 16384];                           \
        const int kb = (t) * 64;                                              \
        stage_chunk(A, row0, 512, kb,      b_,         2 * w,     l);         \
        stage_chunk(A, row0, 512, kb,      b_,         2 * w + 1, l);         \
        stage_chunk(A, row0, 512, kb + 32, b_ + 4096,  2 * w,     l);         \
        stage_chunk(A, row0, 512, kb + 32, b_ + 4096,  2 * w + 1, l);         \
        stage_chunk(W, colb, 512, kb,      b_ + 8192,  2 * w,     l);         \
        stage_chunk(W, colb, 512, kb,      b_ + 8192,  2 * w + 1, l);         \
        stage_chunk(W, colb, 512, kb + 32, b_ + 12288, 2 * w,     l);         \
        stage_chunk(W, colb, 512, kb + 32, b_ + 12288, 2 * w + 1, l);         \
    }
    STGH(0)
#pragma unroll
    for (int t = 0; t < 8; ++t) {
        if (t < 7) {
            STGH(t + 1)
            asm volatile("s_waitcnt vmcnt(8)" ::: "memory");   // OWN stage(t) done
        } else {
            asm volatile("s_waitcnt vmcnt(0)" ::: "memory");
        }
        __builtin_amdgcn_s_barrier();       // all waves' stage(t) visible
        const unsigned short* b_ = &S[(t & 1) * 16384];
        bf16x8 a[4][2], b[4][2];
#pragma unroll
        for (int mi = 0; mi < 4; ++mi) {
            a[mi][0] = ldf2(b_,        wr * 64 + mi * 16, l);
            a[mi][1] = ldf2(b_ + 4096, wr * 64 + mi * 16, l);
        }
#pragma unroll
        for (int nj = 0; nj < 4; ++nj) {
            b[nj][0] = ldf2(b_ + 8192,  wc * 64 + nj * 16, l);
            b[nj][1] = ldf2(b_ + 12288, wc * 64 + nj * 16, l);
        }
        __builtin_amdgcn_s_setprio(1);
#pragma unroll
        for (int mi = 0; mi < 4; ++mi)
#pragma unroll
            for (int nj = 0; nj < 4; ++nj) {
                acc[mi][nj] = MFMA16(a[mi][0], b[nj][0], acc[mi][nj]);
                acc[mi][nj] = MFMA16(a[mi][1], b[nj][1], acc[mi][nj]);
            }
        __builtin_amdgcn_s_setprio(0);
        __builtin_amdgcn_s_barrier();       // reads of buf[t&1] done -> reusable
    }
#undef STGH

    // epilogue: gelu -> S [128][136] bf16 -> ushort8 stores
#pragma unroll
    for (int mi = 0; mi < 4; ++mi) {
        const int R0 = wr * 64 + mi * 16 + (l >> 4) * 4;
#pragma unroll
        for (int nj = 0; nj < 4; ++nj) {
            const int C = wc * 64 + nj * 16 + (l & 15);
            const float bv = bias[colb + C];
#pragma unroll
            for (int q = 0; q < 4; ++q)
                S[(R0 + q) * 136 + C] = f2bf(geluf(acc[mi][nj][q] + bv));
        }
    }
    __syncthreads();
#pragma unroll
    for (int s = 0; s < 8; ++s) {
        const int flat = s * 2048 + tid * 8;
        const int row = flat >> 7;
        const int col = flat & 127;
        ushort8 vv = *(const ushort8*)&S[row * 136 + col];
        *(ushort8*)(O + (row0 + row) * 256 + colb + col) = vv;
    }
}

// ---------------- K4: G2[8192][512] = gy @ WoR^T + b_out (fp32) — r9 ------------
__launch_bounds__(256)
__global__ void g2calc(const unsigned short* __restrict__ Gy,
                       const unsigned short* __restrict__ Wo,
                       const float* __restrict__ bo,
                       float* __restrict__ G2) {
    __shared__ __align__(16) unsigned short S[32768];
    const int tid = threadIdx.x;
    const int w = tid >> 6, l = tid & 63;
    const int wr = w >> 1, wc = w & 1;
    const int mt = blockIdx.x >> 2;
    const int nt = blockIdx.x & 3;
    const long row0 = (long)mt * 128 + wr * 64;
    const long col0 = (long)nt * 128 + wc * 64;

    unsigned short* aw[2] = { &S[w * 4096],        &S[16384 + w * 4096] };
    unsigned short* bw[2] = { &S[w * 4096 + 2048], &S[16384 + w * 4096 + 2048] };

    f32x4 acc[4][4];
    const f32x4 z4 = {0.f, 0.f, 0.f, 0.f};
#pragma unroll
    for (int i = 0; i < 4; ++i)
#pragma unroll
        for (int j = 0; j < 4; ++j) acc[i][j] = z4;

    stage_w(Gy, row0, 256, 0, aw[0], l);
    stage_w(Wo, col0, 512, 256, bw[0], l);

#pragma unroll
    for (int t = 0; t < 8; ++t) {
        if (t < 7) {
            stage_w(Gy, row0, 256, (t + 1) * 32, aw[(t + 1) & 1], l);
            stage_w(Wo, col0, 512, 256 + (t + 1) * 32, bw[(t + 1) & 1], l);
            asm volatile("s_waitcnt vmcnt(8)" ::: "memory");
        } else {
            asm volatile("s_waitcnt vmcnt(0)" ::: "memory");
        }
        const unsigned short* ab = aw[t & 1];
        const unsigned short* bbuf = bw[t & 1];
        bf16x8 af[4], bfr[4];
#pragma unroll
        for (int mi = 0; mi < 4; ++mi) af[mi] = ldw(ab, mi * 16, l);
#pragma unroll
        for (int nj = 0; nj < 4; ++nj) bfr[nj] = ldw(bbuf, nj * 16, l);
#pragma unroll
        for (int mi = 0; mi < 4; ++mi)
#pragma unroll
            for (int nj = 0; nj < 4; ++nj)
                acc[mi][nj] = MFMA16(af[mi], bfr[nj], acc[mi][nj]);
    }

#pragma unroll
    for (int mi = 0; mi < 4; ++mi) {
        const long rb = row0 + mi * 16 + (l >> 4) * 4;
#pragma unroll
        for (int nj = 0; nj < 4; ++nj) {
            const long cg = col0 + nj * 16 + (l & 15);
            const float bv = bo[cg];
#pragma unroll
            for (int q = 0; q < 4; ++q)
                G2[(rb + q) * 512 + cg] = acc[mi][nj][q] + bv;
        }
    }
}

// ---------------- K5: z[row][r] = (h . v)/512, streaming A, Vt-resident (r9) ----
__launch_bounds__(256)
__global__ void zcalc_s(const unsigned short* __restrict__ Hp,   // [65536][256]
                        const unsigned short* __restrict__ Gy,   // [8192][256]
                        const float* __restrict__ v,             // [128][512][8]
                        unsigned short* __restrict__ zb) {       // [65536][8] bf16
    __shared__ __align__(16) unsigned short Vt[16 * 536];        // [r 16 (8..15 zero)][i 512]
    const int tid = threadIdx.x;
    const int w = tid >> 6, l = tid & 63;
    const int mt = blockIdx.x;           // 0..511
    const long row0 = (long)mt * 128;
    const int gb = (mt >> 5) * 512 + (mt & 3) * 128;   // gy row base
    {
        ushort8 zz = {0, 0, 0, 0, 0, 0, 0, 0};
        for (int i = tid; i < (16 * 536) / 8; i += 256) *(ushort8*)&Vt[i * 8] = zz;
        __syncthreads();
        const float* vp = v + (long)(mt >> 2) * 4096;
#pragma unroll
        for (int p = 0; p < 4; ++p) {
            float4_t vv = *(const float4_t*)(vp + tid * 16 + p * 4);
#pragma unroll
            for (int j = 0; j < 4; ++j) {
                int flat = tid * 16 + p * 4 + j;   // = i*8 + r
                Vt[(flat & 7) * 536 + (flat >> 3)] = f2bf(vv[j] * (1.0f / 512.0f));
            }
        }
        __syncthreads();
    }
    const unsigned short* ph[2];
    const unsigned short* pg[2];
#pragma unroll
    for (int q = 0; q < 2; ++q) {
        const int r = (w * 2 + q) * 16 + (l & 15);
        ph[q] = Hp + (row0 + r) * 256 + (l >> 4) * 8;
        pg[q] = Gy + (size_t)(gb + r) * 256 + (l >> 4) * 8;
    }
    f32x4 zacc[2];
    const f32x4 z4 = {0.f, 0.f, 0.f, 0.f};
    zacc[0] = z4; zacc[1] = z4;
#pragma unroll
    for (int ks = 0; ks < 8; ++ks) {
        bf16x8 bv = lds8(&Vt[(l & 15) * 536 + ks * 32 + (l >> 4) * 8]);
#pragma unroll
        for (int q = 0; q < 2; ++q)
            zacc[q] = MFMA16(lds8(ph[q] + ks * 32), bv, zacc[q]);
    }
#pragma unroll
    for (int ks = 0; ks < 8; ++ks) {
        bf16x8 bv = lds8(&Vt[(l & 15) * 536 + 256 + ks * 32 + (l >> 4) * 8]);
#pragma unroll
        for (int q = 0; q < 2; ++q)
            zacc[q] = MFMA16(lds8(pg[q] + ks * 32), bv, zacc[q]);
    }
    if ((l & 15) < 8) {
#pragma unroll
        for (int q = 0; q < 2; ++q) {
            const int fr = w * 2 + q;
#pragma unroll
            for (int reg = 0; reg < 4; ++reg) {
                long r = row0 + fr * 16 + (l >> 4) * 4 + reg;
                zb[r * 8 + (l & 15)] = f2bf(zacc[q][reg]);
            }
        }
    }
}

// ---- K6: out = gelu(hp @ WoL^T + G2 + b + z.u^T/8). 128x128 tile, K=256 ->
// 4 BK=64 steps, shared staging, race-free two-barrier; lora+G2 epilogue.
__launch_bounds__(256)
__global__ void gemm_out2(const unsigned short* __restrict__ Hp,  // [65536][256]
                          const unsigned short* __restrict__ Wo,  // [512][512]
                          const float* __restrict__ bbi,          // [16][512]
                          const float* __restrict__ u,            // [128][512][8]
                          const unsigned short* __restrict__ zb,  // [65536][8]
                          const float* __restrict__ G2,           // [8192][512]
                          float* __restrict__ Out) {               // [65536][512]
    __shared__ __align__(16) unsigned short S[32768];   // 64 KB
    const int tid = threadIdx.x;
    const int w = tid >> 6, l = tid & 63;
    const int wr = w >> 1, wc = w & 1;
    const int work = ((blockIdx.x & 7) * 256) + (blockIdx.x >> 3);  // 2048 wgs
    const int nt = work & 3;
    const int mt = work >> 2;
    const long row0 = (long)mt * 128;
    const long colb = (long)nt * 128;
    const int bk = mt >> 2;
    const int bi = bk >> 3;
    const long g2b = (long)bi * 512 + (mt & 3) * 128;   // G2 row base

    f32x4 acc[4][4];
    const f32x4 z4 = {0.f, 0.f, 0.f, 0.f};
#pragma unroll
    for (int i = 0; i < 4; ++i)
#pragma unroll
        for (int j = 0; j < 4; ++j) acc[i][j] = z4;

#define STGO(t)                                                               \
    {                                                                         \
        unsigned short* b_ = &S[((t) & 1) * 16384];                           \
        const int kb = (t) * 64;                                              \
        stage_chunk(Hp, row0, 256, kb,      b_,         2 * w,     l);        \
        stage_chunk(Hp, row0, 256, kb,      b_,         2 * w + 1, l);        \
        stage_chunk(Hp, row0, 256, kb + 32, b_ + 4096,  2 * w,     l);        \
        stage_chunk(Hp, row0, 256, kb + 32, b_ + 4096,  2 * w + 1, l);        \
        stage_chunk(Wo, colb, 512, kb,      b_ + 8192,  2 * w,     l);        \
        stage_chunk(Wo, colb, 512, kb,      b_ + 8192,  2 * w + 1, l);        \
        stage_chunk(Wo, colb, 512, kb + 32, b_ + 12288, 2 * w,     l);        \
        stage_chunk(Wo, colb, 512, kb + 32, b_ + 12288, 2 * w + 1, l);        \
    }
    STGO(0)
#pragma unroll
    for (int t = 0; t < 4; ++t) {
        if (t < 3) {
            STGO(t + 1)
            asm volatile("s_waitcnt vmcnt(8)" ::: "memory");   // OWN stage(t) done
        } else {
            asm volatile("s_waitcnt vmcnt(0)" ::: "memory");
        }
        __builtin_amdgcn_s_barrier();       // all waves' stage(t) visible
        const unsigned short* b_ = &S[(t & 1) * 16384];
        bf16x8 a[4][2], b[4][2];
#pragma unroll
        for (int mi = 0; mi < 4; ++mi) {
            a[mi][0] = ldf2(b_,        wr * 64 + mi * 16, l);
            a[mi][1] = ldf2(b_ + 4096, wr * 64 + mi * 16, l);
        }
#pragma unroll
        for (int nj = 0; nj < 4; ++nj) {
            b[nj][0] = ldf2(b_ + 8192,  wc * 64 + nj * 16, l);
            b[nj][1] = ldf2(b_ + 12288, wc * 64 + nj * 16, l);
        }
        __builtin_amdgcn_s_setprio(1);
#pragma unroll
        for (int mi = 0; mi < 4; ++mi)
#pragma unroll
            for (int nj = 0; nj < 4; ++nj) {
                acc[mi][nj] = MFMA16(a[mi][0], b[nj][0], acc[mi][nj]);
                acc[mi][nj] = MFMA16(a[mi][1], b[nj][1], acc[mi][nj]);
            }
        __builtin_amdgcn_s_setprio(0);
        __builtin_amdgcn_s_barrier();       // reads of buf[t&1] done -> reusable
    }
#undef STGO

    // park z (zero-padded to k=32) into S[0..4095] (linear [128][32]), lora MFMA
    {
        ushort8 zz = {0, 0, 0, 0, 0, 0, 0, 0};
        const int row = tid >> 1;
        if ((tid & 1) == 0) {
            *(ushort8*)&S[row * 32]     = *(const ushort8*)&zb[(row0 + row) * 8];
            *(ushort8*)&S[row * 32 + 8] = zz;
        } else {
            *(ushort8*)&S[row * 32 + 16] = zz;
            *(ushort8*)&S[row * 32 + 24] = zz;
        }
    }
    __syncthreads();

    const float* up = u + (long)bk * 4096;
#pragma unroll
    for (int nj = 0; nj < 4; ++nj) {
        const long og = colb + wc * 64 + nj * 16 + (l & 15);
        ushort8 ubits = {0, 0, 0, 0, 0, 0, 0, 0};
        if ((l >> 4) == 0) {
            float4_t u0 = *(const float4_t*)(up + og * 8);
            float4_t u1 = *(const float4_t*)(up + og * 8 + 4);
            ubits[0] = f2bf(u0[0] * 0.125f); ubits[1] = f2bf(u0[1] * 0.125f);
            ubits[2] = f2bf(u0[2] * 0.125f); ubits[3] = f2bf(u0[3] * 0.125f);
            ubits[4] = f2bf(u1[0] * 0.125f); ubits[5] = f2bf(u1[1] * 0.125f);
            ubits[6] = f2bf(u1[2] * 0.125f); ubits[7] = f2bf(u1[3] * 0.125f);
        }
        bf16x8 ub = __builtin_bit_cast(bf16x8, ubits);
#pragma unroll
        for (int mi = 0; mi < 4; ++mi) {
            bf16x8 az = lds8(&S[(wr * 64 + mi * 16 + (l & 15)) * 32 + (l >> 4) * 8]);
            acc[mi][nj] = MFMA16(az, ub, acc[mi][nj]);
        }
    }

    // epilogue: + bbi + G2, gelu, nontemporal fp32 stores
#pragma unroll
    for (int nj = 0; nj < 4; ++nj) {
        const long og = colb + wc * 64 + nj * 16 + (l & 15);
        const float badd = bbi[bi * 512 + og];
#pragma unroll
        for (int mi = 0; mi < 4; ++mi) {
            const int R0 = wr * 64 + mi * 16 + (l >> 4) * 4;
#pragma unroll
            for (int q = 0; q < 4; ++q) {
                const float g2v = G2[(g2b + R0 + q) * 512 + og];
                __builtin_nontemporal_store(
                    geluf(acc[mi][nj][q] + badd + g2v),
                    Out + (row0 + R0 + q) * 512 + og);
            }
        }
    }
}

extern "C" void kernel_launch(void* const* d_in, const int* in_sizes, int n_in,
                              void* d_out, int out_size, void* d_ws, size_t ws_size,
                              hipStream_t stream) {
    const float* x  = (const float*)d_in[0];
    const float* u  = (const float*)d_in[1];
    const float* v  = (const float*)d_in[2];
    const float* bb = (const float*)d_in[3];
    const float* Wp = (const float*)d_in[4];
    const float* bp = (const float*)d_in[5];
    const float* Wa = (const float*)d_in[6];
    const float* ba = (const float*)d_in[7];
    const float* Wo = (const float*)d_in[8];
    const float* bo = (const float*)d_in[9];
    float* out = (float*)d_out;

    // workspace (within the proven 114,294,784-byte footprint):
    //   xb [0,64MB) — dead after gemm_hp; G2 (16 MB) and zb (1 MB) alias into it
    char* ws = (char*)d_ws;
    unsigned short* xb  = (unsigned short*)(ws + 0);          // 67,108,864 B [65536][512]
    float*          G2  = (float*)(ws + 0);                   // 16 MB (aliases dead xb)
    unsigned short* zb  = (unsigned short*)(ws + 16777216);   //  1 MB (aliases dead xb)
    unsigned short* xm  = (unsigned short*)(ws + 67108864);   //  8,388,608 B [8192][512]
    unsigned short* gy  = (unsigned short*)(ws + 75497472);   //  4,194,304 B [8192][256]
    unsigned short* hp  = (unsigned short*)(ws + 79691776);   // 33,554,432 B [65536][256]
    unsigned short* Wpb = (unsigned short*)(ws + 113246208);  //    262,144 B
    unsigned short* Wab = (unsigned short*)(ws + 113508352);  //    262,144 B
    unsigned short* Wob = (unsigned short*)(ws + 113770496);  //    524,288 B (total 114,294,784)

    cvt_all<<<512, 256, 0, stream>>>(Wp, Wa, Wo, Wpb, Wab, Wob);
    mean_cvt<<<2048, 256, 0, stream>>>(x, xb, xm);
    // gy = gelu(xm @ W_ave^T + b_ave): M=8192
    gemm_gelu<<<128, 256, 0, stream>>>(xm, Wab, ba, gy, 16);
    // hp = gelu(xb @ W_pass^T + b_pass): 1024 blocks, 2 blk/CU (xb dead after)
    gemm_hp<<<1024, 256, 0, stream>>>(xb, Wpb, bp, hp);
    // G2 = gy @ WoR^T + b_out (into dead xb region)
    g2calc<<<256, 256, 0, stream>>>(gy, Wob, bo, G2);
    // z = (h . v)/512 (into dead xb region)
    zcalc_s<<<512, 256, 0, stream>>>(hp, gy, v, zb);
    // out = gelu(hp @ WoL^T + G2 + b + lora): 2048 blocks, K=256 -> 4 steps
    gemm_out2<<<2048, 256, 0, stream>>>(hp, Wob, bb, u, zb, G2, out);
}

// Round 18
// 138.156 us; speedup vs baseline: 1.0784x; 1.0784x over previous
//
#include <hip/hip_runtime.h>
#include <stdint.h>

// Problem constants: B=16, K=8, F=512, INCH=512, OUTCH=512, R=8
// rows M = B*K*F = 65536; "bk" index = b*8+k (128 slices of 512 rows)
// Algebra: h = [hp | gy_bcast]; out = gelu(hp @ WoL^T + G2[b,f] + b + z.u^T/8),
//          G2 = gy @ WoR^T + b_out;  z = (hp.vL + gy.vR)/512
// Round 18: r16 (best, 141.8us) + vectorized fused epilogue: two-pass LDS
// transpose -> float4 G2 loads + float4 nontemporal Out stores.

typedef __attribute__((ext_vector_type(8))) __bf16 bf16x8;
typedef __attribute__((ext_vector_type(4))) float f32x4;
typedef __attribute__((ext_vector_type(8))) unsigned short ushort8;
typedef __attribute__((ext_vector_type(4))) unsigned short ushort4_t;
typedef __attribute__((ext_vector_type(4))) float float4_t;

#define MFMA16(a, b, c) __builtin_amdgcn_mfma_f32_16x16x32_bf16((a), (b), (c), 0, 0, 0)
#define GLL16(g, l)                                                                   \
    __builtin_amdgcn_global_load_lds((const __attribute__((address_space(1))) void*)(g), \
                                     (__attribute__((address_space(3))) void*)(l), 16, 0, 0)

__device__ inline unsigned short f2bf(float f) {
    union { float fv; unsigned u; } un; un.fv = f;
    unsigned u = un.u;
    u += 0x7FFFu + ((u >> 16) & 1u);   // RNE
    return (unsigned short)(u >> 16);
}

// fast gelu: x * sigmoid(1.5957691*(x + 0.044715 x^3)); max |err| vs exact ~2.5e-4
__device__ inline float geluf(float x) {
    float x2 = x * x;
    float inner = x + 0.044715f * x * x2;
    float e = __expf(-1.5957691216057308f * inner);
    return x * __builtin_amdgcn_rcpf(1.0f + e);
}

__device__ inline bf16x8 lds8(const unsigned short* p) {
    return __builtin_bit_cast(bf16x8, *(const ushort8*)p);
}

// ---- chunk-granular staging: chunk c = 16 rows x 32 k = one GLL16 per wave.
// logical k-granule j of row r lives at phys slot j ^ (r&3) ^ ((r>>2)&3);
// swizzle via per-lane GLOBAL source addr, LDS dest linear (GLL16 rule).
__device__ inline void stage_chunk(const unsigned short* __restrict__ src, long rowbase,
                                   long stride, int k0, unsigned short* buf, int c, int l) {
    const int r = c * 16 + (l >> 2);
    const int j = (l & 3) ^ ((l >> 2) & 3) ^ (l >> 4);
    GLL16(src + (rowbase + r) * stride + k0 + j * 8, &buf[c * 512]);
}

// read logical (row rbase+(l&15), granule l>>4) from a chunked [rows][32] buf
__device__ inline bf16x8 ldf2(const unsigned short* buf, int rbase, int l) {
    const int r = rbase + (l & 15);
    const int slot = (l >> 4) ^ (r & 3) ^ ((r >> 2) & 3);
    return lds8(&buf[r * 32 + slot * 8]);
}

// ---- per-WAVE private 64x32 staging (wave reads only its own staged chunks ->
// per-wave vmcnt is a sufficient fence) ------------------------------------------
__device__ inline void stage_w(const unsigned short* __restrict__ src, long rowbase,
                               long stride, int k0, unsigned short* buf, int l) {
#pragma unroll
    for (int it = 0; it < 4; ++it) {
        const int s = it * 64 + l;
        const int r = s >> 2;
        const int j = (s & 3) ^ (r & 3);
        GLL16(src + (rowbase + r) * stride + k0 + j * 8, &buf[it * 512]);
    }
}

__device__ inline bf16x8 ldw(const unsigned short* buf, int rbase, int l) {
    const int r = rbase + (l & 15);
    const int j = l >> 4;
    return lds8(&buf[r * 32 + (((j ^ r) & 3) << 3)]);
}

// ---------------- K0: all three weight mats fp32 -> bf16 in one launch ----------
__global__ void cvt_all(const float* __restrict__ a, const float* __restrict__ b,
                        const float* __restrict__ c, unsigned short* __restrict__ oa,
                        unsigned short* __restrict__ ob, unsigned short* __restrict__ oc) {
    int bid = blockIdx.x;                // 512 blocks: 128 Wp, 128 Wa, 256 Wo
    const float* s; unsigned short* d; int off;
    if (bid < 128) { s = a; d = oa; off = bid; }
    else if (bid < 256) { s = b; d = ob; off = bid - 128; }
    else { s = c; d = oc; off = bid - 256; }
    int i = off * 256 + threadIdx.x;     // float4 index
    float4_t v = *(const float4_t*)(s + (size_t)i * 4);
    ushort4_t r;
    r[0] = f2bf(v[0]); r[1] = f2bf(v[1]); r[2] = f2bf(v[2]); r[3] = f2bf(v[3]);
    *(ushort4_t*)(d + (size_t)i * 4) = r;
}

// ---------------- K1: mean over K + x -> bf16, 16B stores.  grid 2048 x 256 -----
__global__ void mean_cvt(const float* __restrict__ x,
                         unsigned short* __restrict__ xb,
                         unsigned short* __restrict__ xm) {
    int gid = blockIdx.x * 256 + threadIdx.x;   // B*F*64 = 524288 threads
    int c  = gid & 63;
    int bf = gid >> 6;
    int b  = bf >> 9;
    int f  = bf & 511;
    float s0 = 0.f, s1 = 0.f, s2 = 0.f, s3 = 0.f, s4 = 0.f, s5 = 0.f, s6 = 0.f, s7 = 0.f;
#pragma unroll
    for (int k = 0; k < 8; ++k) {
        long row = (long)(b * 8 + k) * 512 + f;
        float4_t lo = *(const float4_t*)(x + row * 512 + c * 8);
        float4_t hi = *(const float4_t*)(x + row * 512 + c * 8 + 4);
        s0 += lo[0]; s1 += lo[1]; s2 += lo[2]; s3 += lo[3];
        s4 += hi[0]; s5 += hi[1]; s6 += hi[2]; s7 += hi[3];
        ushort8 t;
        t[0] = f2bf(lo[0]); t[1] = f2bf(lo[1]); t[2] = f2bf(lo[2]); t[3] = f2bf(lo[3]);
        t[4] = f2bf(hi[0]); t[5] = f2bf(hi[1]); t[6] = f2bf(hi[2]); t[7] = f2bf(hi[3]);
        *(ushort8*)(xb + row * 512 + c * 8) = t;
    }
    ushort8 m;
    m[0] = f2bf(s0 * 0.125f); m[1] = f2bf(s1 * 0.125f);
    m[2] = f2bf(s2 * 0.125f); m[3] = f2bf(s3 * 0.125f);
    m[4] = f2bf(s4 * 0.125f); m[5] = f2bf(s5 * 0.125f);
    m[6] = f2bf(s6 * 0.125f); m[7] = f2bf(s7 * 0.125f);
    *(ushort8*)(xm + (long)bf * 512 + c * 8) = m;
}

// ------- K2: gy[8192][256] = gelu(xm @ Wa^T + ba) — r9 structure (wave-private) -
__launch_bounds__(256)
__global__ void gemm_gelu(const unsigned short* __restrict__ A,
                          const unsigned short* __restrict__ W,
                          const float* __restrict__ bias,
                          unsigned short* __restrict__ O,
                          int chunk) {
    __shared__ __align__(16) unsigned short S[32768];
    const int tid = threadIdx.x;
    const int w = tid >> 6, l = tid & 63;
    const int wr = w >> 1, wc = w & 1;
    const int work = ((blockIdx.x & 7) * chunk) + (blockIdx.x >> 3);
    const int nt = work & 1;
    const int mt = work >> 1;
    const long row0 = (long)mt * 128 + wr * 64;
    const long col0 = (long)nt * 128 + wc * 64;

    unsigned short* aw[2] = { &S[w * 4096],        &S[16384 + w * 4096] };
    unsigned short* bw[2] = { &S[w * 4096 + 2048], &S[16384 + w * 4096 + 2048] };

    f32x4 acc[4][4];
    const f32x4 z4 = {0.f, 0.f, 0.f, 0.f};
#pragma unroll
    for (int i = 0; i < 4; ++i)
#pragma unroll
        for (int j = 0; j < 4; ++j) acc[i][j] = z4;

    stage_w(A, row0, 512, 0, aw[0], l);
    stage_w(W, col0, 512, 0, bw[0], l);

#pragma unroll
    for (int t = 0; t < 16; ++t) {
        if (t < 15) {
            stage_w(A, row0, 512, (t + 1) * 32, aw[(t + 1) & 1], l);
            stage_w(W, col0, 512, (t + 1) * 32, bw[(t + 1) & 1], l);
            asm volatile("s_waitcnt vmcnt(8)" ::: "memory");
        } else {
            asm volatile("s_waitcnt vmcnt(0)" ::: "memory");
        }
        const unsigned short* ab = aw[t & 1];
        const unsigned short* bbuf = bw[t & 1];
        bf16x8 af[4], bfr[4];
#pragma unroll
        for (int mi = 0; mi < 4; ++mi) af[mi] = ldw(ab, mi * 16, l);
#pragma unroll
        for (int nj = 0; nj < 4; ++nj) bfr[nj] = ldw(bbuf, nj * 16, l);
        __builtin_amdgcn_s_setprio(1);
#pragma unroll
        for (int mi = 0; mi < 4; ++mi)
#pragma unroll
            for (int nj = 0; nj < 4; ++nj)
                acc[mi][nj] = MFMA16(af[mi], bfr[nj], acc[mi][nj]);
        __builtin_amdgcn_s_setprio(0);
    }

    __syncthreads();
    const int colblk = nt * 128;
#pragma unroll
    for (int mi = 0; mi < 4; ++mi) {
        const int R0 = wr * 64 + mi * 16 + (l >> 4) * 4;
#pragma unroll
        for (int nj = 0; nj < 4; ++nj) {
            const int C = wc * 64 + nj * 16 + (l & 15);
            const float bv = bias[colblk + C];
#pragma unroll
            for (int q = 0; q < 4; ++q)
                S[(R0 + q) * 136 + C] = f2bf(geluf(acc[mi][nj][q] + bv));
        }
    }
    __syncthreads();
    const long rowt = (long)mt * 128;
#pragma unroll
    for (int s = 0; s < 8; ++s) {
        const int flat = s * 2048 + tid * 8;
        const int row = flat >> 7;
        const int col = flat & 127;
        ushort8 vv = *(const ushort8*)&S[row * 136 + col];
        *(ushort8*)(O + (rowt + row) * 256 + colblk + col) = vv;
    }
}

// ---------------- K3: G2[8192][512] = gy @ WoR^T + b_out (fp32) — r9 ------------
__launch_bounds__(256)
__global__ void g2calc(const unsigned short* __restrict__ Gy,
                       const unsigned short* __restrict__ Wo,
                       const float* __restrict__ bo,
                       float* __restrict__ G2) {
    __shared__ __align__(16) unsigned short S[32768];
    const int tid = threadIdx.x;
    const int w = tid >> 6, l = tid & 63;
    const int wr = w >> 1, wc = w & 1;
    const int mt = blockIdx.x >> 2;
    const int nt = blockIdx.x & 3;
    const long row0 = (long)mt * 128 + wr * 64;
    const long col0 = (long)nt * 128 + wc * 64;

    unsigned short* aw[2] = { &S[w * 4096],        &S[16384 + w * 4096] };
    unsigned short* bw[2] = { &S[w * 4096 + 2048], &S[16384 + w * 4096 + 2048] };

    f32x4 acc[4][4];
    const f32x4 z4 = {0.f, 0.f, 0.f, 0.f};
#pragma unroll
    for (int i = 0; i < 4; ++i)
#pragma unroll
        for (int j = 0; j < 4; ++j) acc[i][j] = z4;

    stage_w(Gy, row0, 256, 0, aw[0], l);
    stage_w(Wo, col0, 512, 256, bw[0], l);

#pragma unroll
    for (int t = 0; t < 8; ++t) {
        if (t < 7) {
            stage_w(Gy, row0, 256, (t + 1) * 32, aw[(t + 1) & 1], l);
            stage_w(Wo, col0, 512, 256 + (t + 1) * 32, bw[(t + 1) & 1], l);
            asm volatile("s_waitcnt vmcnt(8)" ::: "memory");
        } else {
            asm volatile("s_waitcnt vmcnt(0)" ::: "memory");
        }
        const unsigned short* ab = aw[t & 1];
        const unsigned short* bbuf = bw[t & 1];
        bf16x8 af[4], bfr[4];
#pragma unroll
        for (int mi = 0; mi < 4; ++mi) af[mi] = ldw(ab, mi * 16, l);
#pragma unroll
        for (int nj = 0; nj < 4; ++nj) bfr[nj] = ldw(bbuf, nj * 16, l);
#pragma unroll
        for (int mi = 0; mi < 4; ++mi)
#pragma unroll
            for (int nj = 0; nj < 4; ++nj)
                acc[mi][nj] = MFMA16(af[mi], bfr[nj], acc[mi][nj]);
    }

#pragma unroll
    for (int mi = 0; mi < 4; ++mi) {
        const long rb = row0 + mi * 16 + (l >> 4) * 4;
#pragma unroll
        for (int nj = 0; nj < 4; ++nj) {
            const long cg = col0 + nj * 16 + (l & 15);
            const float bv = bo[cg];
#pragma unroll
            for (int q = 0; q < 4; ++q)
                G2[(rb + q) * 512 + cg] = acc[mi][nj][q] + bv;
        }
    }
}

// ---- K4: FUSED @ BK=64, race-free two-barrier steps (r16) + vectorized epilogue.
// LDS map (ushorts): hp_t @0 (32768 — doubles as GEMM1 stage buf1),
//   Sreg @32768 (32768 — GEMM1 buf0; GEMM2 bufs), Vt @65536 (8576),
//   Zs @74112 (4096). Total 78208 ushorts = 152.75 KB. All dead by epilogue ->
//   reused as SMf [64][516] fp32 (two row-half passes).
__launch_bounds__(512)
__global__ void fused_out(const unsigned short* __restrict__ xb,   // [65536][512]
                          const unsigned short* __restrict__ Wp,   // [256][512]
                          const float* __restrict__ bp,            // [256]
                          const unsigned short* __restrict__ Gy,   // [8192][256]
                          const unsigned short* __restrict__ Wo,   // [512][512]
                          const float* __restrict__ bbi,           // [16][512]
                          const float* __restrict__ u,             // [128][512][8]
                          const float* __restrict__ v,             // [128][512][8]
                          const float* __restrict__ G2,            // [8192][512]
                          float* __restrict__ Out) {                // [65536][512]
    __shared__ __align__(16) unsigned short SM[78208];
    unsigned short* hp_t = &SM[0];
    unsigned short* Sreg = &SM[32768];
    unsigned short* Vt   = &SM[65536];    // [16][536], rows 8..15 zero
    unsigned short* Zs   = &SM[74112];    // [128][32] zero-padded z

    const int tid = threadIdx.x;
    const int w = tid >> 6, l = tid & 63;
    const int wm = w >> 2, wn = w & 3;               // 2 x 4 wave grid
    const int mt = ((blockIdx.x & 7) * 64) + (blockIdx.x >> 3);   // XCD bijection, 512 wgs
    const long row0 = (long)mt * 128;
    const int bk = mt >> 2;
    const int bi = bk >> 3;
    const int f0 = (mt & 3) * 128;
    const long gyb = (long)bi * 512 + f0;            // gy/G2 row base

    const f32x4 zero4 = {0.f, 0.f, 0.f, 0.f};

    // ===== GEMM1: hp_t = gelu(xb[128x512] @ Wp[256x512]^T + bp), BK=64, 8 steps ==
#define STG1(t)                                                               \
    {                                                                         \
        unsigned short* b_ = ((t) & 1) ? hp_t : Sreg;                         \
        const int kb_ = (t) * 64;                                             \
        stage_chunk(xb, row0, 512, kb_,      b_,         w, l);               \
        stage_chunk(xb, row0, 512, kb_ + 32, b_ + 4096,  w, l);               \
        stage_chunk(Wp, 0,    512, kb_,      b_ + 8192,  2 * w,     l);       \
        stage_chunk(Wp, 0,    512, kb_,      b_ + 8192,  2 * w + 1, l);       \
        stage_chunk(Wp, 0,    512, kb_ + 32, b_ + 16384, 2 * w,     l);       \
        stage_chunk(Wp, 0,    512, kb_ + 32, b_ + 16384, 2 * w + 1, l);       \
    }
    {
        f32x4 acc[4][4];
#pragma unroll
        for (int i = 0; i < 4; ++i)
#pragma unroll
            for (int j = 0; j < 4; ++j) acc[i][j] = zero4;

        STG1(0)
#pragma unroll
        for (int t = 0; t < 8; ++t) {
            if (t < 7) {
                STG1(t + 1)
                asm volatile("s_waitcnt vmcnt(6)" ::: "memory");   // OWN stage(t) done
            } else {
                asm volatile("s_waitcnt vmcnt(0)" ::: "memory");
            }
            __builtin_amdgcn_s_barrier();   // ALL waves' stage(t) now visible
            const unsigned short* b_ = (t & 1) ? hp_t : Sreg;
            bf16x8 a[4][2], b[4][2];
#pragma unroll
            for (int mi = 0; mi < 4; ++mi) {
                a[mi][0] = ldf2(b_,        wm * 64 + mi * 16, l);
                a[mi][1] = ldf2(b_ + 4096, wm * 64 + mi * 16, l);
            }
#pragma unroll
            for (int nj = 0; nj < 4; ++nj) {
                b[nj][0] = ldf2(b_ + 8192,  wn * 64 + nj * 16, l);
                b[nj][1] = ldf2(b_ + 16384, wn * 64 + nj * 16, l);
            }
            __builtin_amdgcn_s_setprio(1);
#pragma unroll
            for (int mi = 0; mi < 4; ++mi)
#pragma unroll
                for (int nj = 0; nj < 4; ++nj) {
                    acc[mi][nj] = MFMA16(a[mi][0], b[nj][0], acc[mi][nj]);
                    acc[mi][nj] = MFMA16(a[mi][1], b[nj][1], acc[mi][nj]);
                }
            __builtin_amdgcn_s_setprio(0);
            __builtin_amdgcn_s_barrier();   // reads of buf[t&1] done -> reusable
        }

        // write hp_t (gelu, granule-swizzled: granule j of row r at slot j^(r&31))
#pragma unroll
        for (int mi = 0; mi < 4; ++mi) {
            const int R0 = wm * 64 + mi * 16 + (l >> 4) * 4;
#pragma unroll
            for (int nj = 0; nj < 4; ++nj) {
                const int C = wn * 64 + nj * 16 + (l & 15);
                const float bv = bp[C];
#pragma unroll
                for (int q = 0; q < 4; ++q) {
                    const int row = R0 + q;
                    const int slot = (C >> 3) ^ (row & 31);
                    hp_t[row * 256 + slot * 8 + (C & 7)] =
                        f2bf(geluf(acc[mi][nj][q] + bv));
                }
            }
        }
        ushort8 zz = {0, 0, 0, 0, 0, 0, 0, 0};
        *(ushort8*)&Zs[tid * 8] = zz;                    // 512*8 = 4096 ushorts
        for (int i = tid; i < 1072; i += 512) *(ushort8*)&Vt[i * 8] = zz;
    }
#undef STG1
    __syncthreads();     // hp_t complete; Sreg free; Vt/Zs zeroed

    // ===== GEMM2 prologue stage (overlaps z) + Vt fill ===========================
#define STG2(s)                                                               \
    {                                                                         \
        const int ch_ = (s) >> 2, kk_ = ((s) & 3) * 64;                       \
        unsigned short* b_ = Sreg + ((s) & 1) * 16384;                        \
        stage_chunk(Wo, (long)ch_ * 256, 512, kk_,      b_,        2 * w,     l); \
        stage_chunk(Wo, (long)ch_ * 256, 512, kk_,      b_,        2 * w + 1, l); \
        stage_chunk(Wo, (long)ch_ * 256, 512, kk_ + 32, b_ + 8192, 2 * w,     l); \
        stage_chunk(Wo, (long)ch_ * 256, 512, kk_ + 32, b_ + 8192, 2 * w + 1, l); \
    }
    {
        STG2(0)
        const float* vp = v + (long)bk * 4096;
        float4_t v0 = *(const float4_t*)(vp + tid * 8);
        float4_t v1 = *(const float4_t*)(vp + tid * 8 + 4);
#pragma unroll
        for (int j = 0; j < 8; ++j) {
            const int flat = tid * 8 + j;                // = i*8 + r
            const float val = (j < 4 ? v0[j] : v1[j - 4]) * (1.0f / 512.0f);
            Vt[(flat & 7) * 536 + (flat >> 3)] = f2bf(val);
        }
        asm volatile("s_waitcnt vmcnt(0)" ::: "memory");
    }
    __syncthreads();     // Vt ready + stage(0) visible everywhere

    // ================= z = (hp.vL + gy.vR)/512, wave w owns rows w*16..+15 =======
    {
        f32x4 zacc = zero4;
        const int zrow = w * 16 + (l & 15);
#pragma unroll
        for (int ks = 0; ks < 8; ++ks) {
            const int jw = ks * 4 + (l >> 4);
            bf16x8 av = lds8(&hp_t[zrow * 256 + ((jw ^ (zrow & 31)) * 8)]);
            bf16x8 bv = lds8(&Vt[(l & 15) * 536 + ks * 32 + (l >> 4) * 8]);
            zacc = MFMA16(av, bv, zacc);
        }
        const unsigned short* grow = Gy + (gyb + zrow) * 256 + (l >> 4) * 8;
#pragma unroll
        for (int ks = 0; ks < 8; ++ks) {
            bf16x8 bv = lds8(&Vt[(l & 15) * 536 + 256 + ks * 32 + (l >> 4) * 8]);
            zacc = MFMA16(lds8(grow + ks * 32), bv, zacc);
        }
        if ((l & 15) < 8) {
#pragma unroll
            for (int reg = 0; reg < 4; ++reg)
                Zs[(w * 16 + (l >> 4) * 4 + reg) * 32 + (l & 15)] = f2bf(zacc[reg]);
        }
        asm volatile("s_waitcnt lgkmcnt(0)" ::: "memory");  // Zs drained pre-barrier
    }

    // ===== GEMM2: out = hp_t @ Wo^T, BK=64, 8 steps (2 ch x 4 kk) ================
    f32x4 acc2[2][4][4];
#pragma unroll
    for (int c = 0; c < 2; ++c)
#pragma unroll
        for (int i = 0; i < 4; ++i)
#pragma unroll
            for (int j = 0; j < 4; ++j) acc2[c][i][j] = zero4;

#pragma unroll
    for (int ch = 0; ch < 2; ++ch) {
#pragma unroll
        for (int kk = 0; kk < 4; ++kk) {
            const int s = ch * 4 + kk;
            if (s < 7) {
                STG2(s + 1)
                asm volatile("s_waitcnt vmcnt(4)" ::: "memory");   // OWN stage(s) done
            } else {
                asm volatile("s_waitcnt vmcnt(0)" ::: "memory");
            }
            __builtin_amdgcn_s_barrier();   // ALL waves' stage(s) visible (+Zs @ s=0)
            const unsigned short* b_ = Sreg + (s & 1) * 16384;
            bf16x8 a[4][2], b[4][2];
#pragma unroll
            for (int mi = 0; mi < 4; ++mi) {
                const int row = wm * 64 + mi * 16 + (l & 15);
#pragma unroll
                for (int ks = 0; ks < 2; ++ks) {
                    const int jw = kk * 8 + ks * 4 + (l >> 4);
                    a[mi][ks] = lds8(&hp_t[row * 256 + ((jw ^ (row & 31)) * 8)]);
                }
            }
#pragma unroll
            for (int nj = 0; nj < 4; ++nj) {
                b[nj][0] = ldf2(b_,        wn * 64 + nj * 16, l);
                b[nj][1] = ldf2(b_ + 8192, wn * 64 + nj * 16, l);
            }
            __builtin_amdgcn_s_setprio(1);
#pragma unroll
            for (int mi = 0; mi < 4; ++mi)
#pragma unroll
                for (int nj = 0; nj < 4; ++nj) {
                    acc2[ch][mi][nj] = MFMA16(a[mi][0], b[nj][0], acc2[ch][mi][nj]);
                    acc2[ch][mi][nj] = MFMA16(a[mi][1], b[nj][1], acc2[ch][mi][nj]);
                }
            __builtin_amdgcn_s_setprio(0);
            __builtin_amdgcn_s_barrier();   // reads of buf[s&1] done -> reusable
        }
    }
#undef STG2

    // ================= lora: acc2 += z @ (u/8)^T  (zero-padded MFMA) =============
    const float* up = u + (long)bk * 4096;
#pragma unroll
    for (int ch = 0; ch < 2; ++ch) {
#pragma unroll
        for (int nj = 0; nj < 4; ++nj) {
            const int og = ch * 256 + wn * 64 + nj * 16 + (l & 15);
            ushort8 ubits = {0, 0, 0, 0, 0, 0, 0, 0};
            if ((l >> 4) == 0) {
                float4_t u0 = *(const float4_t*)(up + og * 8);
                float4_t u1 = *(const float4_t*)(up + og * 8 + 4);
                ubits[0] = f2bf(u0[0] * 0.125f); ubits[1] = f2bf(u0[1] * 0.125f);
                ubits[2] = f2bf(u0[2] * 0.125f); ubits[3] = f2bf(u0[3] * 0.125f);
                ubits[4] = f2bf(u1[0] * 0.125f); ubits[5] = f2bf(u1[1] * 0.125f);
                ubits[6] = f2bf(u1[2] * 0.125f); ubits[7] = f2bf(u1[3] * 0.125f);
            }
            bf16x8 ub = __builtin_bit_cast(bf16x8, ubits);
#pragma unroll
            for (int mi = 0; mi < 4; ++mi) {
                bf16x8 az = lds8(&Zs[(wm * 64 + mi * 16 + (l & 15)) * 32 + (l >> 4) * 8]);
                acc2[ch][mi][nj] = MFMA16(az, ub, acc2[ch][mi][nj]);
            }
        }
    }

    // ===== epilogue (vectorized): two passes of 64 rows. Owner half-waves write
    // acc2+bbi into SMf[64][516]; all waves then do float4 G2-add+gelu+store.
    float* SMf = (float*)SM;   // 64*516*4 B = 132,096 B <= 156,416 B available
#pragma unroll
    for (int p = 0; p < 2; ++p) {
        __builtin_amdgcn_s_barrier();        // prior SM readers done (lora / pass p-1)
        if (wm == p) {
#pragma unroll
            for (int ch = 0; ch < 2; ++ch) {
#pragma unroll
                for (int nj = 0; nj < 4; ++nj) {
                    const int col = ch * 256 + wn * 64 + nj * 16 + (l & 15);
                    const float badd = bbi[bi * 512 + col];
#pragma unroll
                    for (int mi = 0; mi < 4; ++mi) {
                        const int R0 = mi * 16 + (l >> 4) * 4;
#pragma unroll
                        for (int q = 0; q < 4; ++q)
                            SMf[(R0 + q) * 516 + col] = acc2[ch][mi][nj][q] + badd;
                    }
                }
            }
        }
        __syncthreads();                     // SMf visible to all
#pragma unroll
        for (int it = 0; it < 16; ++it) {
            const int idx = it * 512 + tid;  // 8192 float4 slots
            const int rl = idx >> 7;         // 0..63
            const int c4 = (idx & 127) * 4;  // col
            float4_t vv = *(const float4_t*)&SMf[rl * 516 + c4];
            float4_t g4 = *(const float4_t*)(G2 + (gyb + p * 64 + rl) * 512 + c4);
            float4_t o4;
            o4[0] = geluf(vv[0] + g4[0]); o4[1] = geluf(vv[1] + g4[1]);
            o4[2] = geluf(vv[2] + g4[2]); o4[3] = geluf(vv[3] + g4[3]);
            __builtin_nontemporal_store(
                o4, (float4_t*)(Out + (row0 + p * 64 + rl) * 512 + c4));
        }
    }
}

extern "C" void kernel_launch(void* const* d_in, const int* in_sizes, int n_in,
                              void* d_out, int out_size, void* d_ws, size_t ws_size,
                              hipStream_t stream) {
    const float* x  = (const float*)d_in[0];
    const float* u  = (const float*)d_in[1];
    const float* v  = (const float*)d_in[2];
    const float* bb = (const float*)d_in[3];
    const float* Wp = (const float*)d_in[4];
    const float* bp = (const float*)d_in[5];
    const float* Wa = (const float*)d_in[6];
    const float* ba = (const float*)d_in[7];
    const float* Wo = (const float*)d_in[8];
    const float* bo = (const float*)d_in[9];
    float* out = (float*)d_out;

    char* ws = (char*)d_ws;
    unsigned short* xb  = (unsigned short*)(ws + 0);          // 67,108,864 B [65536][512]
    unsigned short* xm  = (unsigned short*)(ws + 67108864);   //  8,388,608 B [8192][512]
    unsigned short* gy  = (unsigned short*)(ws + 75497472);   //  4,194,304 B [8192][256]
    float*          G2  = (float*)(ws + 79691776);            // 16,777,216 B [8192][512]
    unsigned short* Wpb = (unsigned short*)(ws + 96468992);   //    262,144 B
    unsigned short* Wab = (unsigned short*)(ws + 96731136);   //    262,144 B
    unsigned short* Wob = (unsigned short*)(ws + 96993280);   //    524,288 B (total ~97.5 MB)

    cvt_all<<<512, 256, 0, stream>>>(Wp, Wa, Wo, Wpb, Wab, Wob);
    mean_cvt<<<2048, 256, 0, stream>>>(x, xb, xm);
    // gy = gelu(xm @ W_ave^T + b_ave): M=8192
    gemm_gelu<<<128, 256, 0, stream>>>(xm, Wab, ba, gy, 16);
    // G2 = gy @ WoR^T + b_out
    g2calc<<<256, 256, 0, stream>>>(gy, Wob, bo, G2);
    // fused: hp (LDS-only) -> z -> out
    fused_out<<<512, 512, 0, stream>>>(xb, Wpb, bp, gy, Wob, bb, u, v, G2, out);
}